// Round 8
// baseline (2381.824 us; speedup 1.0000x reference)
//
#include <hip/hip_runtime.h>
#include <cstdint>
#include <cstddef>

#define DD   768
#define HHN  12
#define SS   197
#define FFD  3072
#define MROWS 3152   // B*S
#define MPAD  3200   // padded rows (25 * 128)
#define PROWS 3136   // B*196 patches
#define PSTRIDE 2457600  // 3200*768 floats: one split-K partial (padded rows)

typedef __attribute__((ext_vector_type(4))) float  f32x4;
typedef __attribute__((ext_vector_type(8))) __bf16 bf16x8;
typedef __attribute__((ext_vector_type(4))) __bf16 bf16x4;

// ---------------------------------------------------------------------------
// Weight pre-transform, ALL tensors in one dispatch, ZERO LDS:
// W[K][N] fp32 -> Wb[k/8][n][k%8] bf16 via pure register transpose.
// NONTEMPORAL on both streams: W is read-once, Wb is write-once (consumed
// much later) -> bypass L2/L3 allocation so the two 171-342 MB streams stop
// fighting for cache (r7: all in-kernel suspects eliminated, still 2.5 TB/s).
__global__ __launch_bounds__(256) void w2ball_k(
    const float* __restrict__ Wp, const float* __restrict__ Wq, const float* __restrict__ Wk,
    const float* __restrict__ Wv, const float* __restrict__ Wo, const float* __restrict__ W1,
    const float* __restrict__ W2,
    __bf16* __restrict__ Wpb, __bf16* __restrict__ Wqb, __bf16* __restrict__ Wkb,
    __bf16* __restrict__ Wvb, __bf16* __restrict__ Wob, __bf16* __restrict__ W1b,
    __bf16* __restrict__ W2b)
{
  const int bidx = blockIdx.x;
  const float* W; __bf16* Wb; int NT, loc;   // NT = N/256 tiles
  if      (bidx <    72) { W = Wp; Wb = Wpb; NT =  3; loc = bidx;        }  // 768x768
  else if (bidx <   936) { W = Wq; Wb = Wqb; NT =  3; loc = bidx - 72;   }  // 9216x768
  else if (bidx <  1800) { W = Wk; Wb = Wkb; NT =  3; loc = bidx - 936;  }
  else if (bidx <  2664) { W = Wv; Wb = Wvb; NT =  3; loc = bidx - 1800; }
  else if (bidx <  3528) { W = Wo; Wb = Wob; NT =  3; loc = bidx - 2664; }
  else if (bidx <  6984) { W = W1; Wb = W1b; NT = 12; loc = bidx - 3528; }  // 9216x3072
  else                   { W = W2; Wb = W2b; NT =  3; loc = bidx - 6984; }  // 36864x768
  const int N  = NT * 256;
  const int n0 = (loc % NT) * 256, k0 = (loc / NT) * 32;

  const int t  = threadIdx.x;
  const int kg = t >> 6;                 // 8-row group (one per wave)
  const int n  = n0 + (t & 63) * 4;      // 4 consecutive cols

  const int kb = k0 + kg * 8;
  f32x4 v[8];
  #pragma unroll
  for (int j = 0; j < 8; ++j)
    v[j] = __builtin_nontemporal_load((const f32x4*)(W + (size_t)(kb + j) * N + n));

  __bf16* out = Wb + ((size_t)((k0 >> 3) + kg) * N + n) * 8;
  #pragma unroll
  for (int c = 0; c < 4; ++c) {
    bf16x8 o;
    #pragma unroll
    for (int j = 0; j < 8; ++j) o[j] = (__bf16)v[j][c];
    __builtin_nontemporal_store(o, (bf16x8*)(out + c * 8));
  }
}

// ---------------------------------------------------------------------------
// Pipelined bf16-MFMA GEMM (verified 128^2 structure), 2-D XCD-PATCH swizzle:
//   xcd = blockIdx.x % 8 (HW round-robin); each XCD owns a 2D patch of tiles
//   (4 m-bands x 2 n-bands, m-fastest within patch) -> L2 working set =
//   A-band + B-slab (< 4 MB), weights fetched once per XCD.
//  BN: 128 or 64. BM=128, BK=32, 4 waves, 3 LDS buffers, prefetch distance 2.
//  MODE 0: bias (+opt GELU) -> Cb bf16 / Cf f32.
//  MODE 1: legacy atomicAdd into Cf (unused).
//  MODE 2: split-K partial, NONTEMPORAL f32 store to Cf + kz*PSTRIDE
//          (write-once stream; keep L2 for weights/activations).
template<int BN, int NMAT, int MODE, bool GELU_, bool STOREBF, bool VT>
__global__ __launch_bounds__(256) void gemm_k(
    const __bf16* __restrict__ A,
    const __bf16* __restrict__ Bb0, const __bf16* __restrict__ Bb1, const __bf16* __restrict__ Bb2,
    const float* __restrict__ bias0, const float* __restrict__ bias1, const float* __restrict__ bias2,
    float* __restrict__ Cf, __bf16* __restrict__ Cb, __bf16* __restrict__ vt,
    int N, int Kloc, int Kstride)
{
  // ---- 2D patch swizzle (RM=4, RN=2; requires N/BN even)
  const int xcd = blockIdx.x & 7;
  const int ib  = blockIdx.x >> 3;
  const int NT  = N / BN;
  const int pm  = xcd >> 1, pn = xcd & 1;
  const int cm  = 6 + (pm < 1 ? 1 : 0);            // 25 m-tiles: 7,6,6,6
  const int bm  = pm * 6 + (pm < 1 ? pm : 1);
  const int cn  = NT >> 1;
  if (ib >= cm * cn) return;
  const int mt  = bm + ib % cm;                    // m-fastest: B-tile reused
  const int nt  = pn * cn + ib / cm;               //   back-to-back in L2
  const int m0  = mt * 128;
  const int n0  = nt * BN;
  const int kz  = blockIdx.y;
  const size_t kOff = (size_t)kz * Kloc;

  constexpr int BUFB = (BN == 128) ? 16384 : 12288;
  __shared__ char lds[3 * BUFB];
  const int tid = threadIdx.x;

  int mat = 0, nB = n0, NBw = N;
  const __bf16* Bbp = Bb0; const float* biasp = bias0;
  if (NMAT == 3) {
    mat = n0 / DD; nB = n0 - mat * DD; NBw = DD;
    Bbp   = (mat == 0) ? Bb0   : ((mat == 1) ? Bb1   : Bb2);
    biasp = (mat == 0) ? bias0 : ((mat == 1) ? bias1 : bias2);
  }

  constexpr int NC = (BN == 128) ? 4 : 2;
  f32x4 acc[4][NC];
  const f32x4 z4 = {0.f, 0.f, 0.f, 0.f};
  #pragma unroll
  for (int i = 0; i < 4; ++i)
    #pragma unroll
    for (int j = 0; j < NC; ++j) acc[i][j] = z4;

  const int lane = tid & 63;
  const int wv = tid >> 6;
  const int wr = wv >> 1, wc = wv & 1;
  const int arow = tid & 127, akh = tid >> 7;

  const int nKB = Kloc >> 5;

  auto issue = [&](int kt, int buf) {
    const int k0 = kt << 5;
    char* Ab = lds + buf * BUFB;
    char* Bbl = Ab + 8192;
    {   // A: 2 x 16B DMA per thread
      const __bf16* ga0 = A + (size_t)(m0 + arow) * Kstride + kOff + k0 + akh * 8;
      auto g0 = (__attribute__((address_space(1))) unsigned int*)(uintptr_t)ga0;
      auto g1 = (__attribute__((address_space(1))) unsigned int*)(uintptr_t)(ga0 + 16);
      auto l0 = (__attribute__((address_space(3))) unsigned int*)(uintptr_t)(Ab + wv * 1024);
      auto l1 = (__attribute__((address_space(3))) unsigned int*)(uintptr_t)(Ab + 4096 + wv * 1024);
      __builtin_amdgcn_global_load_lds(g0, l0, 16, 0, 0);
      __builtin_amdgcn_global_load_lds(g1, l1, 16, 0, 0);
    }
    if (BN == 128) {
      #pragma unroll
      for (int r = 0; r < 2; ++r) {
        const int c = r * 256 + tid;
        const int g = c >> 7, col = c & 127;
        const __bf16* gb = Bbp + ((size_t)(((kOff + k0) >> 3) + g) * NBw + nB + col) * 8;
        auto gp = (__attribute__((address_space(1))) unsigned int*)(uintptr_t)gb;
        auto lp = (__attribute__((address_space(3))) unsigned int*)(uintptr_t)(Bbl + r * 4096 + wv * 1024);
        __builtin_amdgcn_global_load_lds(gp, lp, 16, 0, 0);
      }
    } else {
      const __bf16* gb = Bbp + ((size_t)(((kOff + k0) >> 3) + wv) * NBw + nB + lane) * 8;
      auto gp = (__attribute__((address_space(1))) unsigned int*)(uintptr_t)gb;
      auto lp = (__attribute__((address_space(3))) unsigned int*)(uintptr_t)(Bbl + wv * 1024);
      __builtin_amdgcn_global_load_lds(gp, lp, 16, 0, 0);
    }
  };

  constexpr int WAITIMM = (BN == 128) ? 0xF78 /*vmcnt(8)*/ : 0xF76 /*vmcnt(6)*/;

  issue(0, 0);
  issue(nKB > 1 ? 1 : 0, 1);

  int cb = 0, wb = 2;
  const int q = lane >> 4, r16 = lane & 15;
  for (int kb = 0; kb < nKB; ++kb) {
    __builtin_amdgcn_sched_barrier(0);
    __builtin_amdgcn_s_barrier();          // WAR: buf wb free
    const int nxt = kb + 2;
    issue(nxt < nKB ? nxt : nKB - 1, wb);  // clamped tail -> never-read buffer
    __builtin_amdgcn_s_waitcnt(WAITIMM);   // tile kb landed (this wave)
    __builtin_amdgcn_s_barrier();          // tile kb landed (all waves)
    __builtin_amdgcn_sched_barrier(0);

    const char* Ab = lds + cb * BUFB;
    const char* Bbl = Ab + 8192;
    const char* pa = Ab + q * 2048 + (wr * 64 + r16) * 16;
    const char* pb = (BN == 128) ? (Bbl + q * 2048 + (wc * 64 + r16) * 16)
                                 : (Bbl + q * 1024 + (wc * 32 + r16) * 16);
    bf16x8 af[4], bfv[NC];
    #pragma unroll
    for (int i = 0; i < 4; ++i) af[i]  = *(const bf16x8*)(pa + i * 256);
    #pragma unroll
    for (int i = 0; i < NC; ++i) bfv[i] = *(const bf16x8*)(pb + i * 256);
    #pragma unroll
    for (int ri = 0; ri < 4; ++ri)
      #pragma unroll
      for (int ci = 0; ci < NC; ++ci)
        acc[ri][ci] = __builtin_amdgcn_mfma_f32_16x16x32_bf16(af[ri], bfv[ci], acc[ri][ci], 0, 0, 0);

    cb = (cb == 2) ? 0 : cb + 1;
    wb = (wb == 2) ? 0 : wb + 1;
  }
  __builtin_amdgcn_s_waitcnt(0);   // drain tail DMAs

  // ---- epilogue: D layout col=lane&15, row=(lane>>4)*4+reg
  const int q4 = (lane >> 4) * 4, c16 = lane & 15;
  #pragma unroll
  for (int ci = 0; ci < NC; ++ci) {
    const int n = n0 + ((BN == 128) ? wc * 64 : wc * 32) + ci * 16 + c16;
    const float bsv = ((MODE == 1 || MODE == 2) && kz != 0) ? 0.f
                      : biasp[(NMAT == 3) ? (n - mat * DD) : n];
    #pragma unroll
    for (int ri = 0; ri < 4; ++ri) {
      const int mb = m0 + wr * 64 + ri * 16 + q4;
      #pragma unroll
      for (int rg = 0; rg < 4; ++rg) {
        float v = acc[ri][ci][rg] + bsv;
        const int row = mb + rg;
        if (VT && NMAT == 3 && mat == 2) {
          // scatter V into PV B-operand layout: vt[b][h][s/8][d][s%8]
          const int b = row / SS;
          if (b < 16) {
            const int s = row - b * SS;
            const int nloc = n - 2 * DD;
            const int hh = nloc >> 6, d = nloc & 63;
            vt[((size_t)(b * HHN + hh) * 28 + (s >> 3)) * 512 + d * 8 + (s & 7)] = (__bf16)v;
          }
        } else {
          const size_t off = (size_t)row * N + n;
          if (MODE == 1) {
            atomicAdd(&Cf[off], v);
          } else if (MODE == 2) {
            __builtin_nontemporal_store(v, &Cf[(size_t)kz * PSTRIDE + off]);
          } else {
            if (GELU_) {
              const float zz = v;
              const float a = 0.7978845608028654f * (zz + 0.044715f * zz * zz * zz);
              v = 0.5f * zz * (2.0f - 2.0f / (1.0f + __expf(2.0f * a)));
            }
            if (STOREBF) Cb[off] = (__bf16)v; else Cf[off] = v;
          }
        }
      }
    }
  }
}

// ---------------------------------------------------------------------------
// Fused MFMA attention: one block per (b, h, 64-row q-tile). grid (4, 192).
__global__ __launch_bounds__(256) void attn_k(const __bf16* __restrict__ qkv,
                                              const __bf16* __restrict__ vt,
                                              __bf16* __restrict__ att)
{
  __shared__ char als[58240];
  const int t = threadIdx.x;
  const int qt = blockIdx.x, bh = blockIdx.y;
  const int b = bh / HHN, hh = bh % HHN;
  const int r0 = qt * 64;

  bf16x8 vstage[7];
  #pragma unroll
  for (int i = 0; i < 7; ++i)
    vstage[i] = *(const bf16x8*)(vt + (size_t)bh * 14336 + (size_t)(t + i * 256) * 8);

  #pragma unroll
  for (int i = 0; i < 7; ++i) {
    const int c = t + i * 256;
    const int kh = c & 7, s = c >> 3;
    const int sg = s < SS ? s : (SS - 1);
    const bf16x8 v = *(const bf16x8*)(qkv + (size_t)(b * SS + sg) * 2304 + DD + hh * 64 + kh * 8);
    *(bf16x8*)(als + kh * 3600 + s * 16) = v;
  }
  #pragma unroll
  for (int i = 0; i < 2; ++i) {
    const int c = t + i * 256;
    const int qr = c & 63, dh8 = c >> 6;
    const int rr = r0 + qr;
    const int sg = rr < SS ? rr : (SS - 1);
    const bf16x8 v = *(const bf16x8*)(qkv + (size_t)(b * SS + sg) * 2304 + hh * 64 + dh8 * 8);
    *(bf16x8*)(als + 28800 + dh8 * 1040 + qr * 16) = v;
  }
  __syncthreads();

  const int w = t >> 6, lane = t & 63;
  const int q = lane >> 4, c16 = lane & 15;
  const f32x4 z4 = {0.f, 0.f, 0.f, 0.f};

  f32x4 acc[13];
  #pragma unroll
  for (int nt = 0; nt < 13; ++nt) acc[nt] = z4;
  #pragma unroll
  for (int kk = 0; kk < 2; ++kk) {
    const bf16x8 af = *(const bf16x8*)(als + 28800 + (kk * 4 + q) * 1040 + (w * 16 + c16) * 16);
    #pragma unroll
    for (int nt = 0; nt < 13; ++nt) {
      const bf16x8 bf_ = *(const bf16x8*)(als + (kk * 4 + q) * 3600 + (nt * 16 + c16) * 16);
      acc[nt] = __builtin_amdgcn_mfma_f32_16x16x32_bf16(af, bf_, acc[nt], 0, 0, 0);
    }
  }
  __syncthreads();   // Ks/Qs dead; LDS reused below

  float inv[4];
  #pragma unroll
  for (int rg = 0; rg < 4; ++rg) {
    float mx = -1e30f;
    #pragma unroll
    for (int nt = 0; nt < 13; ++nt) {
      const bool val = (nt < 12) || (c16 < 5);
      const float sv = acc[nt][rg] * 0.125f;
      if (val) mx = fmaxf(mx, sv);
    }
    #pragma unroll
    for (int m = 1; m < 16; m <<= 1) mx = fmaxf(mx, __shfl_xor(mx, m, 16));
    float sm = 0.f;
    #pragma unroll
    for (int nt = 0; nt < 13; ++nt) {
      const bool val = (nt < 12) || (c16 < 5);
      const float e = val ? __expf(acc[nt][rg] * 0.125f - mx) : 0.f;
      acc[nt][rg] = e; sm += e;
    }
    #pragma unroll
    for (int m = 1; m < 16; m <<= 1) sm += __shfl_xor(sm, m, 16);
    inv[rg] = 1.f / sm;
  }

  #pragma unroll
  for (int nt = 0; nt < 14; ++nt) {
    #pragma unroll
    for (int rg = 0; rg < 4; ++rg) {
      const int s = nt * 16 + c16;
      const int qr = w * 16 + q * 4 + rg;
      const float pv = (nt < 13) ? acc[nt][rg] * inv[rg] : 0.f;
      *(__bf16*)(als + (s >> 3) * 1040 + qr * 16 + (s & 7) * 2) = (__bf16)pv;
    }
  }
  #pragma unroll
  for (int i = 0; i < 7; ++i) {
    const int c = t + i * 256;
    *(bf16x8*)(als + 29120 + (c >> 6) * 1040 + (c & 63) * 16) = vstage[i];
  }
  __syncthreads();

  f32x4 o[4];
  #pragma unroll
  for (int dt = 0; dt < 4; ++dt) o[dt] = z4;
  #pragma unroll
  for (int kk = 0; kk < 7; ++kk) {
    const bf16x8 af = *(const bf16x8*)(als + (kk * 4 + q) * 1040 + (w * 16 + c16) * 16);
    #pragma unroll
    for (int dt = 0; dt < 4; ++dt) {
      const bf16x8 bf_ = *(const bf16x8*)(als + 29120 + (kk * 4 + q) * 1040 + (dt * 16 + c16) * 16);
      o[dt] = __builtin_amdgcn_mfma_f32_16x16x32_bf16(af, bf_, o[dt], 0, 0, 0);
    }
  }
  #pragma unroll
  for (int dt = 0; dt < 4; ++dt) {
    #pragma unroll
    for (int rg = 0; rg < 4; ++rg) {
      const int r = r0 + w * 16 + q * 4 + rg;
      if (r < SS)
        att[((size_t)bh * SS + r) * 64 + dt * 16 + c16] = (__bf16)o[dt][rg];
    }
  }
}

// ---------------------------------------------------------------------------
// Row LayerNorm over D=768: 256-thread blocks, 4 rows/block (wave per row).
template<bool OUTBF>
__global__ __launch_bounds__(256) void ln_k(const float* __restrict__ X,
    const float* __restrict__ g, const float* __restrict__ be, float eps,
    __bf16* __restrict__ Yb, float* __restrict__ Yf)
{
  const int row = blockIdx.x * 4 + (threadIdx.x >> 6), l = threadIdx.x & 63;
  const f32x4* xr = (const f32x4*)(X + (size_t)row * DD);
  f32x4 v[3];
  #pragma unroll
  for (int j = 0; j < 3; ++j) v[j] = xr[l + j * 64];
  float s = 0.f;
  #pragma unroll
  for (int j = 0; j < 3; ++j) s += v[j][0] + v[j][1] + v[j][2] + v[j][3];
  #pragma unroll
  for (int m = 1; m < 64; m <<= 1) s += __shfl_xor(s, m, 64);
  const float mean = s * (1.f / 768.f);
  float vs = 0.f;
  #pragma unroll
  for (int j = 0; j < 3; ++j)
    #pragma unroll
    for (int e = 0; e < 4; ++e) { const float d = v[j][e] - mean; vs += d * d; }
  #pragma unroll
  for (int m = 1; m < 64; m <<= 1) vs += __shfl_xor(vs, m, 64);
  const float rstd = rsqrtf(vs * (1.f / 768.f) + eps);
  const f32x4* gp = (const f32x4*)g; const f32x4* bp = (const f32x4*)be;
  #pragma unroll
  for (int j = 0; j < 3; ++j) {
    const int c4 = l + j * 64;
    const f32x4 gg = gp[c4], bb = bp[c4];
    if (OUTBF) {
      bf16x4 o;
      #pragma unroll
      for (int e = 0; e < 4; ++e) o[e] = (__bf16)((v[j][e] - mean) * rstd * gg[e] + bb[e]);
      *(bf16x4*)(Yb + (size_t)row * DD + c4 * 4) = o;
    } else {
      f32x4 o;
      #pragma unroll
      for (int e = 0; e < 4; ++e) o[e] = (v[j][e] - mean) * rstd * gg[e] + bb[e];
      *(f32x4*)(Yf + (size_t)row * DD + c4 * 4) = o;
    }
  }
}

// ---------------------------------------------------------------------------
// Fused split-K reduce + residual + LayerNorm: h_new = X + sum(P[0..NPART)),
// optionally write h_new back (WRITEH), then LN(h_new) -> Yb (bf16) or Yf.
// Partial reads are NONTEMPORAL (read-once stream).
template<int NPART, bool OUTBF, bool WRITEH>
__global__ __launch_bounds__(256) void lnsum_k(const float* X,
    const float* __restrict__ P, const float* __restrict__ g, const float* __restrict__ be,
    float eps, __bf16* __restrict__ Yb, float* __restrict__ Yf, float* Hout)
{
  const int row = blockIdx.x * 4 + (threadIdx.x >> 6), l = threadIdx.x & 63;
  const f32x4* xr = (const f32x4*)(X + (size_t)row * DD);
  f32x4 v[3];
  #pragma unroll
  for (int j = 0; j < 3; ++j) v[j] = xr[l + j * 64];
  #pragma unroll
  for (int p = 0; p < NPART; ++p) {
    const f32x4* pr = (const f32x4*)(P + (size_t)p * PSTRIDE + (size_t)row * DD);
    #pragma unroll
    for (int j = 0; j < 3; ++j) v[j] += __builtin_nontemporal_load(&pr[l + j * 64]);
  }
  if (WRITEH) {
    f32x4* hw = (f32x4*)(Hout + (size_t)row * DD);
    #pragma unroll
    for (int j = 0; j < 3; ++j) hw[l + j * 64] = v[j];
  }
  float s = 0.f;
  #pragma unroll
  for (int j = 0; j < 3; ++j) s += v[j][0] + v[j][1] + v[j][2] + v[j][3];
  #pragma unroll
  for (int m = 1; m < 64; m <<= 1) s += __shfl_xor(s, m, 64);
  const float mean = s * (1.f / 768.f);
  float vs = 0.f;
  #pragma unroll
  for (int j = 0; j < 3; ++j)
    #pragma unroll
    for (int e = 0; e < 4; ++e) { const float d = v[j][e] - mean; vs += d * d; }
  #pragma unroll
  for (int m = 1; m < 64; m <<= 1) vs += __shfl_xor(vs, m, 64);
  const float rstd = rsqrtf(vs * (1.f / 768.f) + eps);
  const f32x4* gp = (const f32x4*)g; const f32x4* bp = (const f32x4*)be;
  #pragma unroll
  for (int j = 0; j < 3; ++j) {
    const int c4 = l + j * 64;
    const f32x4 gg = gp[c4], bb = bp[c4];
    if (OUTBF) {
      bf16x4 o;
      #pragma unroll
      for (int e = 0; e < 4; ++e) o[e] = (__bf16)((v[j][e] - mean) * rstd * gg[e] + bb[e]);
      *(bf16x4*)(Yb + (size_t)row * DD + c4 * 4) = o;
    } else {
      f32x4 o;
      #pragma unroll
      for (int e = 0; e < 4; ++e) o[e] = (v[j][e] - mean) * rstd * gg[e] + bb[e];
      *(f32x4*)(Yf + (size_t)row * DD + c4 * 4) = o;
    }
  }
}

// ---------------------------------------------------------------------------
// im2col, vectorized: each thread owns 16 consecutive patch-cols (48 = 3x16,
// so a 16-col chunk never crosses an image-row segment): 4 x f32x4 loads +
// 2 x bf16x8 stores (was 1 scalar load + 2 B store per thread).
__global__ __launch_bounds__(256) void im2col_k(const float* __restrict__ x, __bf16* __restrict__ patches)
{
  const int idx = blockIdx.x * 256 + threadIdx.x;       // chunk id
  const int row = idx / 48, col0 = (idx % 48) * 16;
  if (row < PROWS) {
    const int b = row / 196, p = row % 196;
    const int py = p / 14, px = p % 14;
    const int r = col0 / 48, o = col0 % 48;             // offset within segment
    const float* src = x + ((size_t)(b * 224 + py * 16 + r) * 224 + px * 16) * 3 + o;
    f32x4 v[4];
    #pragma unroll
    for (int j = 0; j < 4; ++j) v[j] = *(const f32x4*)(src + j * 4);
    bf16x8 o0, o1;
    #pragma unroll
    for (int e = 0; e < 8; ++e) { o0[e] = (__bf16)v[e >> 2][e & 3]; o1[e] = (__bf16)v[2 + (e >> 2)][e & 3]; }
    *(bf16x8*)(patches + (size_t)row * 768 + col0)     = o0;
    *(bf16x8*)(patches + (size_t)row * 768 + col0 + 8) = o1;
  } else if (row < MPAD) {
    const bf16x8 z = {};
    *(bf16x8*)(patches + (size_t)row * 768 + col0)     = z;
    *(bf16x8*)(patches + (size_t)row * 768 + col0 + 8) = z;
  }
}

__global__ __launch_bounds__(256) void assemble_k(const float* __restrict__ tmp, const float* __restrict__ cls,
    const float* __restrict__ pos, float* __restrict__ h)
{
  const int idx = blockIdx.x * 256 + threadIdx.x;
  const int row = idx / 192, qc = (idx % 192) * 4;
  f32x4 v = {0.f, 0.f, 0.f, 0.f};
  if (row < MROWS) {
    const int b = row / SS, s2 = row % SS;
    if (s2 == 0) v = *(const f32x4*)(cls + qc);
    else         v = *(const f32x4*)(tmp + (size_t)(b * 196 + s2 - 1) * 768 + qc);
    const f32x4 p = *(const f32x4*)(pos + (size_t)s2 * 768 + qc);
    v += p;
  }
  *(f32x4*)(h + (size_t)row * 768 + qc) = v;
}

// ---------------------------------------------------------------------------
extern "C" void kernel_launch(void* const* d_in, const int* in_sizes, int n_in,
                              void* d_out, int out_size, void* d_ws, size_t ws_size,
                              hipStream_t stream)
{
  (void)in_sizes; (void)n_in; (void)out_size;
  const float* x    = (const float*)d_in[0];
  const float* cls  = (const float*)d_in[1];
  const float* pos  = (const float*)d_in[2];
  const float* Wp   = (const float*)d_in[3];
  const float* bp   = (const float*)d_in[4];
  const float* Wq   = (const float*)d_in[5];
  const float* bq   = (const float*)d_in[6];
  const float* Wk   = (const float*)d_in[7];
  const float* bk   = (const float*)d_in[8];
  const float* Wv   = (const float*)d_in[9];
  const float* bv   = (const float*)d_in[10];
  const float* Wo   = (const float*)d_in[11];
  const float* bo   = (const float*)d_in[12];
  const float* ln1g = (const float*)d_in[13];
  const float* ln1b = (const float*)d_in[14];
  const float* ln2g = (const float*)d_in[15];
  const float* ln2b = (const float*)d_in[16];
  const float* W1   = (const float*)d_in[17];
  const float* b1   = (const float*)d_in[18];
  const float* W2   = (const float*)d_in[19];
  const float* b2   = (const float*)d_in[20];
  const float* lnfg = (const float*)d_in[21];
  const float* lnfb = (const float*)d_in[22];

  char* ws = (char*)d_ws;
  float*  h    = (float*) (ws + 0);            // 3200x768 f32
  __bf16* y    = (__bf16*)(ws + 9830400);      // 3200x768 bf16
  __bf16* qkv  = (__bf16*)(ws + 14745600);     // 3200x2304 bf16 (v region unused)
  float*  tmp  = (float*) (ws + 14745600);     // alias: patch GEMM out
  __bf16* att  = (__bf16*)(ws + 29491200);     // 3200x768 bf16
  __bf16* mffn = (__bf16*)(ws + 34406400);     // 3200x3072 bf16
  __bf16* patches = (__bf16*)(ws + 34406400);  // alias (pre-layer only)
  __bf16* Wpb = (__bf16*)(ws + 54067200);
  __bf16* Wqb = (__bf16*)(ws + 55246848);
  __bf16* Wkb = (__bf16*)(ws + 69402624);
  __bf16* Wvb = (__bf16*)(ws + 83558400);
  __bf16* Wob = (__bf16*)(ws + 97714176);
  __bf16* W1b = (__bf16*)(ws + 111869952);
  __bf16* W2b = (__bf16*)(ws + 168493056);
  __bf16* vt  = (__bf16*)(ws + 225116160);     // 192 x 28 x 64 x 8 bf16 (5,505,024 B)
  float*  pbuf = (float*)(ws + 230621184);     // 4 x 3200x768 f32 split-K partials
  if (ws_size < 269942784) return;   // failure signature: absmax == ref absmax

  // all weight conversions in ONE dispatch, register transpose, nontemporal
  w2ball_k<<<10440, 256, 0, stream>>>(Wp, Wq, Wk, Wv, Wo, W1, W2,
                                      Wpb, Wqb, Wkb, Wvb, Wob, W1b, W2b);

  im2col_k<<<MPAD * 48 / 256, 256, 0, stream>>>(x, patches);
  // patch GEMM: MODE 2 (plain store + bias, kz=0) -> no atomics, no
  // dependence on tmp being zero-initialized.
  gemm_k<64,1,2,false,false,false><<<12*32, 256, 0, stream>>>(
      patches, Wpb,Wpb,Wpb, bp,bp,bp, tmp, nullptr, nullptr, DD, DD, DD);
  assemble_k<<<MPAD * 192 / 256, 256, 0, stream>>>(tmp, cls, pos, h);

  ln_k<true><<<MROWS / 4, 256, 0, stream>>>(h, ln1g, ln1b, 1e-6f, y, nullptr);
  for (int l = 0; l < 12; ++l) {
    const size_t wDD = (size_t)l * DD * DD, wFF = (size_t)l * DD * FFD;
    // QKV (128^2 tile, 450 working blocks, K=768)
    gemm_k<128,3,0,false,true,true><<<18*32, 256, 0, stream>>>(
        y, Wqb + wDD, Wkb + wDD, Wvb + wDD,
        bq + l*DD, bk + l*DD, bv + l*DD, nullptr, qkv, vt, 3*DD, DD, DD);
    attn_k<<<dim3(4, 192), 256, 0, stream>>>(qkv, vt, att);
    // Wo: split-K x2 -> pbuf[0..1] (600 working blocks, K=384 each)
    gemm_k<64,1,2,false,false,false><<<dim3(12*32, 2), 256, 0, stream>>>(
        att, Wob + wDD, nullptr, nullptr, bo + l*DD, nullptr, nullptr,
        pbuf, nullptr, nullptr, DD, DD/2, DD);
    // h += attn_proj; y = LN2(h)
    lnsum_k<2,true,true><<<MROWS / 4, 256, 0, stream>>>(
        h, pbuf, ln2g + l*DD, ln2b + l*DD, 1e-6f, y, nullptr, h);
    // FFN1 (GELU, bf16 out)
    gemm_k<128,1,0,true,true,false><<<24*32, 256, 0, stream>>>(
        y, W1b + wFF, nullptr, nullptr, b1 + l*FFD, nullptr, nullptr,
        nullptr, mffn, nullptr, FFD, DD, DD);
    // FFN2: split-K x4 -> pbuf[0..3] (600 working blocks, K=768 each)
    gemm_k<128,1,2,false,false,false><<<dim3(6*32, 4), 256, 0, stream>>>(
        mffn, W2b + wFF, nullptr, nullptr, b2 + l*DD, nullptr, nullptr,
        pbuf, nullptr, nullptr, DD, FFD/4, FFD);
    // h += ffn; y = LN1_{l+1}(h)
    if (l < 11)
      lnsum_k<4,true,true><<<MROWS / 4, 256, 0, stream>>>(
          h, pbuf, ln1g + (l+1)*DD, ln1b + (l+1)*DD, 1e-6f, y, nullptr, h);
  }
  lnsum_k<4,false,false><<<MROWS / 4, 256, 0, stream>>>(
      h, pbuf, lnfg, lnfb, 1e-3f, nullptr, (float*)d_out, nullptr);
}

// Round 9
// 2231.989 us; speedup vs baseline: 1.0671x; 1.0671x over previous
//
#include <hip/hip_runtime.h>
#include <cstdint>
#include <cstddef>

#define DD   768
#define HHN  12
#define SS   197
#define FFD  3072
#define MROWS 3152   // B*S
#define MPAD  3200   // padded rows (25 * 128)
#define PROWS 3136   // B*196 patches
#define PSTRIDE 2457600  // 3200*768 floats: one split-K partial (padded rows)

typedef __attribute__((ext_vector_type(4))) float  f32x4;
typedef __attribute__((ext_vector_type(8))) __bf16 bf16x8;
typedef __attribute__((ext_vector_type(4))) __bf16 bf16x4;

// ---------------------------------------------------------------------------
// Weight pre-transform, ALL tensors in one dispatch, ZERO LDS:
// W[K][N] fp32 -> Wb[k/8][n][k%8] bf16 via pure register transpose.
// Thread owns an 8k x 4n micro-tile: 8 x f32x4 coalesced reads, 4 x bf16x8
// contiguous writes. NOTE (r8): nontemporal load/store here REGRESSED
// (WRITE_SIZE 167->300 MB, +35 us) — L2 write-combining helps this stream.
// Externally bound at ~137 us (3 implementations + 1 policy probe plateau).
__global__ __launch_bounds__(256) void w2ball_k(
    const float* __restrict__ Wp, const float* __restrict__ Wq, const float* __restrict__ Wk,
    const float* __restrict__ Wv, const float* __restrict__ Wo, const float* __restrict__ W1,
    const float* __restrict__ W2,
    __bf16* __restrict__ Wpb, __bf16* __restrict__ Wqb, __bf16* __restrict__ Wkb,
    __bf16* __restrict__ Wvb, __bf16* __restrict__ Wob, __bf16* __restrict__ W1b,
    __bf16* __restrict__ W2b)
{
  const int bidx = blockIdx.x;
  const float* W; __bf16* Wb; int NT, loc;   // NT = N/256 tiles
  if      (bidx <    72) { W = Wp; Wb = Wpb; NT =  3; loc = bidx;        }  // 768x768
  else if (bidx <   936) { W = Wq; Wb = Wqb; NT =  3; loc = bidx - 72;   }  // 9216x768
  else if (bidx <  1800) { W = Wk; Wb = Wkb; NT =  3; loc = bidx - 936;  }
  else if (bidx <  2664) { W = Wv; Wb = Wvb; NT =  3; loc = bidx - 1800; }
  else if (bidx <  3528) { W = Wo; Wb = Wob; NT =  3; loc = bidx - 2664; }
  else if (bidx <  6984) { W = W1; Wb = W1b; NT = 12; loc = bidx - 3528; }  // 9216x3072
  else                   { W = W2; Wb = W2b; NT =  3; loc = bidx - 6984; }  // 36864x768
  const int N  = NT * 256;
  const int n0 = (loc % NT) * 256, k0 = (loc / NT) * 32;

  const int t  = threadIdx.x;
  const int kg = t >> 6;                 // 8-row group (one per wave)
  const int n  = n0 + (t & 63) * 4;      // 4 consecutive cols

  const int kb = k0 + kg * 8;
  f32x4 v[8];
  #pragma unroll
  for (int j = 0; j < 8; ++j)
    v[j] = *(const f32x4*)(W + (size_t)(kb + j) * N + n);

  __bf16* out = Wb + ((size_t)((k0 >> 3) + kg) * N + n) * 8;
  #pragma unroll
  for (int c = 0; c < 4; ++c) {
    bf16x8 o;
    #pragma unroll
    for (int j = 0; j < 8; ++j) o[j] = (__bf16)v[j][c];
    *(bf16x8*)(out + c * 8) = o;
  }
}

// ---------------------------------------------------------------------------
// Pipelined bf16-MFMA GEMM (verified 128^2 structure), 2-D XCD-PATCH swizzle:
//   xcd = blockIdx.x % 8 (HW round-robin); each XCD owns a 2D patch of tiles
//   (4 m-bands x 2 n-bands, m-fastest within patch) -> L2 working set =
//   A-band + B-slab (< 4 MB), weights fetched once per XCD.
//  BN: 128 or 64. BM=128, BK=32, 4 waves, 3 LDS buffers, prefetch distance 2.
//  MODE 0: bias (+opt GELU) -> Cb bf16 / Cf f32.
//  MODE 1: legacy atomicAdd into Cf (unused).
//  MODE 2: split-K partial, plain f32 store to Cf + kz*PSTRIDE (bias kz==0).
template<int BN, int NMAT, int MODE, bool GELU_, bool STOREBF, bool VT>
__global__ __launch_bounds__(256) void gemm_k(
    const __bf16* __restrict__ A,
    const __bf16* __restrict__ Bb0, const __bf16* __restrict__ Bb1, const __bf16* __restrict__ Bb2,
    const float* __restrict__ bias0, const float* __restrict__ bias1, const float* __restrict__ bias2,
    float* __restrict__ Cf, __bf16* __restrict__ Cb, __bf16* __restrict__ vt,
    int N, int Kloc, int Kstride)
{
  // ---- 2D patch swizzle (RM=4, RN=2; requires N/BN even)
  const int xcd = blockIdx.x & 7;
  const int ib  = blockIdx.x >> 3;
  const int NT  = N / BN;
  const int pm  = xcd >> 1, pn = xcd & 1;
  const int cm  = 6 + (pm < 1 ? 1 : 0);            // 25 m-tiles: 7,6,6,6
  const int bm  = pm * 6 + (pm < 1 ? pm : 1);
  const int cn  = NT >> 1;
  if (ib >= cm * cn) return;
  const int mt  = bm + ib % cm;                    // m-fastest: B-tile reused
  const int nt  = pn * cn + ib / cm;               //   back-to-back in L2
  const int m0  = mt * 128;
  const int n0  = nt * BN;
  const int kz  = blockIdx.y;
  const size_t kOff = (size_t)kz * Kloc;

  constexpr int BUFB = (BN == 128) ? 16384 : 12288;
  __shared__ char lds[3 * BUFB];
  const int tid = threadIdx.x;

  int mat = 0, nB = n0, NBw = N;
  const __bf16* Bbp = Bb0; const float* biasp = bias0;
  if (NMAT == 3) {
    mat = n0 / DD; nB = n0 - mat * DD; NBw = DD;
    Bbp   = (mat == 0) ? Bb0   : ((mat == 1) ? Bb1   : Bb2);
    biasp = (mat == 0) ? bias0 : ((mat == 1) ? bias1 : bias2);
  }

  constexpr int NC = (BN == 128) ? 4 : 2;
  f32x4 acc[4][NC];
  const f32x4 z4 = {0.f, 0.f, 0.f, 0.f};
  #pragma unroll
  for (int i = 0; i < 4; ++i)
    #pragma unroll
    for (int j = 0; j < NC; ++j) acc[i][j] = z4;

  const int lane = tid & 63;
  const int wv = tid >> 6;
  const int wr = wv >> 1, wc = wv & 1;
  const int arow = tid & 127, akh = tid >> 7;

  const int nKB = Kloc >> 5;

  auto issue = [&](int kt, int buf) {
    const int k0 = kt << 5;
    char* Ab = lds + buf * BUFB;
    char* Bbl = Ab + 8192;
    {   // A: 2 x 16B DMA per thread
      const __bf16* ga0 = A + (size_t)(m0 + arow) * Kstride + kOff + k0 + akh * 8;
      auto g0 = (__attribute__((address_space(1))) unsigned int*)(uintptr_t)ga0;
      auto g1 = (__attribute__((address_space(1))) unsigned int*)(uintptr_t)(ga0 + 16);
      auto l0 = (__attribute__((address_space(3))) unsigned int*)(uintptr_t)(Ab + wv * 1024);
      auto l1 = (__attribute__((address_space(3))) unsigned int*)(uintptr_t)(Ab + 4096 + wv * 1024);
      __builtin_amdgcn_global_load_lds(g0, l0, 16, 0, 0);
      __builtin_amdgcn_global_load_lds(g1, l1, 16, 0, 0);
    }
    if (BN == 128) {
      #pragma unroll
      for (int r = 0; r < 2; ++r) {
        const int c = r * 256 + tid;
        const int g = c >> 7, col = c & 127;
        const __bf16* gb = Bbp + ((size_t)(((kOff + k0) >> 3) + g) * NBw + nB + col) * 8;
        auto gp = (__attribute__((address_space(1))) unsigned int*)(uintptr_t)gb;
        auto lp = (__attribute__((address_space(3))) unsigned int*)(uintptr_t)(Bbl + r * 4096 + wv * 1024);
        __builtin_amdgcn_global_load_lds(gp, lp, 16, 0, 0);
      }
    } else {
      const __bf16* gb = Bbp + ((size_t)(((kOff + k0) >> 3) + wv) * NBw + nB + lane) * 8;
      auto gp = (__attribute__((address_space(1))) unsigned int*)(uintptr_t)gb;
      auto lp = (__attribute__((address_space(3))) unsigned int*)(uintptr_t)(Bbl + wv * 1024);
      __builtin_amdgcn_global_load_lds(gp, lp, 16, 0, 0);
    }
  };

  constexpr int WAITIMM = (BN == 128) ? 0xF78 /*vmcnt(8)*/ : 0xF76 /*vmcnt(6)*/;

  issue(0, 0);
  issue(nKB > 1 ? 1 : 0, 1);

  int cb = 0, wb = 2;
  const int q = lane >> 4, r16 = lane & 15;
  for (int kb = 0; kb < nKB; ++kb) {
    __builtin_amdgcn_sched_barrier(0);
    __builtin_amdgcn_s_barrier();          // WAR: buf wb free
    const int nxt = kb + 2;
    issue(nxt < nKB ? nxt : nKB - 1, wb);  // clamped tail -> never-read buffer
    __builtin_amdgcn_s_waitcnt(WAITIMM);   // tile kb landed (this wave)
    __builtin_amdgcn_s_barrier();          // tile kb landed (all waves)
    __builtin_amdgcn_sched_barrier(0);

    const char* Ab = lds + cb * BUFB;
    const char* Bbl = Ab + 8192;
    const char* pa = Ab + q * 2048 + (wr * 64 + r16) * 16;
    const char* pb = (BN == 128) ? (Bbl + q * 2048 + (wc * 64 + r16) * 16)
                                 : (Bbl + q * 1024 + (wc * 32 + r16) * 16);
    bf16x8 af[4], bfv[NC];
    #pragma unroll
    for (int i = 0; i < 4; ++i) af[i]  = *(const bf16x8*)(pa + i * 256);
    #pragma unroll
    for (int i = 0; i < NC; ++i) bfv[i] = *(const bf16x8*)(pb + i * 256);
    #pragma unroll
    for (int ri = 0; ri < 4; ++ri)
      #pragma unroll
      for (int ci = 0; ci < NC; ++ci)
        acc[ri][ci] = __builtin_amdgcn_mfma_f32_16x16x32_bf16(af[ri], bfv[ci], acc[ri][ci], 0, 0, 0);

    cb = (cb == 2) ? 0 : cb + 1;
    wb = (wb == 2) ? 0 : wb + 1;
  }
  __builtin_amdgcn_s_waitcnt(0);   // drain tail DMAs

  // ---- epilogue: D layout col=lane&15, row=(lane>>4)*4+reg
  const int q4 = (lane >> 4) * 4, c16 = lane & 15;
  #pragma unroll
  for (int ci = 0; ci < NC; ++ci) {
    const int n = n0 + ((BN == 128) ? wc * 64 : wc * 32) + ci * 16 + c16;
    const float bsv = ((MODE == 1 || MODE == 2) && kz != 0) ? 0.f
                      : biasp[(NMAT == 3) ? (n - mat * DD) : n];
    #pragma unroll
    for (int ri = 0; ri < 4; ++ri) {
      const int mb = m0 + wr * 64 + ri * 16 + q4;
      #pragma unroll
      for (int rg = 0; rg < 4; ++rg) {
        float v = acc[ri][ci][rg] + bsv;
        const int row = mb + rg;
        if (VT && NMAT == 3 && mat == 2) {
          // scatter V into PV B-operand layout: vt[b][h][s/8][d][s%8]
          const int b = row / SS;
          if (b < 16) {
            const int s = row - b * SS;
            const int nloc = n - 2 * DD;
            const int hh = nloc >> 6, d = nloc & 63;
            vt[((size_t)(b * HHN + hh) * 28 + (s >> 3)) * 512 + d * 8 + (s & 7)] = (__bf16)v;
          }
        } else {
          const size_t off = (size_t)row * N + n;
          if (MODE == 1) {
            atomicAdd(&Cf[off], v);
          } else if (MODE == 2) {
            Cf[(size_t)kz * PSTRIDE + off] = v;   // plain partial store, no atomics
          } else {
            if (GELU_) {
              const float zz = v;
              const float a = 0.7978845608028654f * (zz + 0.044715f * zz * zz * zz);
              v = 0.5f * zz * (2.0f - 2.0f / (1.0f + __expf(2.0f * a)));
            }
            if (STOREBF) Cb[off] = (__bf16)v; else Cf[off] = v;
          }
        }
      }
    }
  }
}

// ---------------------------------------------------------------------------
// Fused MFMA attention: one block per (b, h, 64-row q-tile). grid (4, 192).
__global__ __launch_bounds__(256) void attn_k(const __bf16* __restrict__ qkv,
                                              const __bf16* __restrict__ vt,
                                              __bf16* __restrict__ att)
{
  __shared__ char als[58240];
  const int t = threadIdx.x;
  const int qt = blockIdx.x, bh = blockIdx.y;
  const int b = bh / HHN, hh = bh % HHN;
  const int r0 = qt * 64;

  bf16x8 vstage[7];
  #pragma unroll
  for (int i = 0; i < 7; ++i)
    vstage[i] = *(const bf16x8*)(vt + (size_t)bh * 14336 + (size_t)(t + i * 256) * 8);

  #pragma unroll
  for (int i = 0; i < 7; ++i) {
    const int c = t + i * 256;
    const int kh = c & 7, s = c >> 3;
    const int sg = s < SS ? s : (SS - 1);
    const bf16x8 v = *(const bf16x8*)(qkv + (size_t)(b * SS + sg) * 2304 + DD + hh * 64 + kh * 8);
    *(bf16x8*)(als + kh * 3600 + s * 16) = v;
  }
  #pragma unroll
  for (int i = 0; i < 2; ++i) {
    const int c = t + i * 256;
    const int qr = c & 63, dh8 = c >> 6;
    const int rr = r0 + qr;
    const int sg = rr < SS ? rr : (SS - 1);
    const bf16x8 v = *(const bf16x8*)(qkv + (size_t)(b * SS + sg) * 2304 + hh * 64 + dh8 * 8);
    *(bf16x8*)(als + 28800 + dh8 * 1040 + qr * 16) = v;
  }
  __syncthreads();

  const int w = t >> 6, lane = t & 63;
  const int q = lane >> 4, c16 = lane & 15;
  const f32x4 z4 = {0.f, 0.f, 0.f, 0.f};

  f32x4 acc[13];
  #pragma unroll
  for (int nt = 0; nt < 13; ++nt) acc[nt] = z4;
  #pragma unroll
  for (int kk = 0; kk < 2; ++kk) {
    const bf16x8 af = *(const bf16x8*)(als + 28800 + (kk * 4 + q) * 1040 + (w * 16 + c16) * 16);
    #pragma unroll
    for (int nt = 0; nt < 13; ++nt) {
      const bf16x8 bf_ = *(const bf16x8*)(als + (kk * 4 + q) * 3600 + (nt * 16 + c16) * 16);
      acc[nt] = __builtin_amdgcn_mfma_f32_16x16x32_bf16(af, bf_, acc[nt], 0, 0, 0);
    }
  }
  __syncthreads();   // Ks/Qs dead; LDS reused below

  float inv[4];
  #pragma unroll
  for (int rg = 0; rg < 4; ++rg) {
    float mx = -1e30f;
    #pragma unroll
    for (int nt = 0; nt < 13; ++nt) {
      const bool val = (nt < 12) || (c16 < 5);
      const float sv = acc[nt][rg] * 0.125f;
      if (val) mx = fmaxf(mx, sv);
    }
    #pragma unroll
    for (int m = 1; m < 16; m <<= 1) mx = fmaxf(mx, __shfl_xor(mx, m, 16));
    float sm = 0.f;
    #pragma unroll
    for (int nt = 0; nt < 13; ++nt) {
      const bool val = (nt < 12) || (c16 < 5);
      const float e = val ? __expf(acc[nt][rg] * 0.125f - mx) : 0.f;
      acc[nt][rg] = e; sm += e;
    }
    #pragma unroll
    for (int m = 1; m < 16; m <<= 1) sm += __shfl_xor(sm, m, 16);
    inv[rg] = 1.f / sm;
  }

  #pragma unroll
  for (int nt = 0; nt < 14; ++nt) {
    #pragma unroll
    for (int rg = 0; rg < 4; ++rg) {
      const int s = nt * 16 + c16;
      const int qr = w * 16 + q * 4 + rg;
      const float pv = (nt < 13) ? acc[nt][rg] * inv[rg] : 0.f;
      *(__bf16*)(als + (s >> 3) * 1040 + qr * 16 + (s & 7) * 2) = (__bf16)pv;
    }
  }
  #pragma unroll
  for (int i = 0; i < 7; ++i) {
    const int c = t + i * 256;
    *(bf16x8*)(als + 29120 + (c >> 6) * 1040 + (c & 63) * 16) = vstage[i];
  }
  __syncthreads();

  f32x4 o[4];
  #pragma unroll
  for (int dt = 0; dt < 4; ++dt) o[dt] = z4;
  #pragma unroll
  for (int kk = 0; kk < 7; ++kk) {
    const bf16x8 af = *(const bf16x8*)(als + (kk * 4 + q) * 1040 + (w * 16 + c16) * 16);
    #pragma unroll
    for (int dt = 0; dt < 4; ++dt) {
      const bf16x8 bf_ = *(const bf16x8*)(als + 29120 + (kk * 4 + q) * 1040 + (dt * 16 + c16) * 16);
      o[dt] = __builtin_amdgcn_mfma_f32_16x16x32_bf16(af, bf_, o[dt], 0, 0, 0);
    }
  }
  #pragma unroll
  for (int dt = 0; dt < 4; ++dt) {
    #pragma unroll
    for (int rg = 0; rg < 4; ++rg) {
      const int r = r0 + w * 16 + q * 4 + rg;
      if (r < SS)
        att[((size_t)bh * SS + r) * 64 + dt * 16 + c16] = (__bf16)o[dt][rg];
    }
  }
}

// ---------------------------------------------------------------------------
// Row LayerNorm over D=768: 256-thread blocks, 4 rows/block (wave per row).
template<bool OUTBF>
__global__ __launch_bounds__(256) void ln_k(const float* __restrict__ X,
    const float* __restrict__ g, const float* __restrict__ be, float eps,
    __bf16* __restrict__ Yb, float* __restrict__ Yf)
{
  const int row = blockIdx.x * 4 + (threadIdx.x >> 6), l = threadIdx.x & 63;
  const f32x4* xr = (const f32x4*)(X + (size_t)row * DD);
  f32x4 v[3];
  #pragma unroll
  for (int j = 0; j < 3; ++j) v[j] = xr[l + j * 64];
  float s = 0.f;
  #pragma unroll
  for (int j = 0; j < 3; ++j) s += v[j][0] + v[j][1] + v[j][2] + v[j][3];
  #pragma unroll
  for (int m = 1; m < 64; m <<= 1) s += __shfl_xor(s, m, 64);
  const float mean = s * (1.f / 768.f);
  float vs = 0.f;
  #pragma unroll
  for (int j = 0; j < 3; ++j)
    #pragma unroll
    for (int e = 0; e < 4; ++e) { const float d = v[j][e] - mean; vs += d * d; }
  #pragma unroll
  for (int m = 1; m < 64; m <<= 1) vs += __shfl_xor(vs, m, 64);
  const float rstd = rsqrtf(vs * (1.f / 768.f) + eps);
  const f32x4* gp = (const f32x4*)g; const f32x4* bp = (const f32x4*)be;
  #pragma unroll
  for (int j = 0; j < 3; ++j) {
    const int c4 = l + j * 64;
    const f32x4 gg = gp[c4], bb = bp[c4];
    if (OUTBF) {
      bf16x4 o;
      #pragma unroll
      for (int e = 0; e < 4; ++e) o[e] = (__bf16)((v[j][e] - mean) * rstd * gg[e] + bb[e]);
      *(bf16x4*)(Yb + (size_t)row * DD + c4 * 4) = o;
    } else {
      f32x4 o;
      #pragma unroll
      for (int e = 0; e < 4; ++e) o[e] = (v[j][e] - mean) * rstd * gg[e] + bb[e];
      *(f32x4*)(Yf + (size_t)row * DD + c4 * 4) = o;
    }
  }
}

// ---------------------------------------------------------------------------
// Fused split-K reduce + residual + LayerNorm: h_new = X + sum(P[0..NPART)),
// optionally write h_new back (WRITEH), then LN(h_new) -> Yb (bf16) or Yf.
template<int NPART, bool OUTBF, bool WRITEH>
__global__ __launch_bounds__(256) void lnsum_k(const float* X,
    const float* __restrict__ P, const float* __restrict__ g, const float* __restrict__ be,
    float eps, __bf16* __restrict__ Yb, float* __restrict__ Yf, float* Hout)
{
  const int row = blockIdx.x * 4 + (threadIdx.x >> 6), l = threadIdx.x & 63;
  const f32x4* xr = (const f32x4*)(X + (size_t)row * DD);
  f32x4 v[3];
  #pragma unroll
  for (int j = 0; j < 3; ++j) v[j] = xr[l + j * 64];
  #pragma unroll
  for (int p = 0; p < NPART; ++p) {
    const f32x4* pr = (const f32x4*)(P + (size_t)p * PSTRIDE + (size_t)row * DD);
    #pragma unroll
    for (int j = 0; j < 3; ++j) v[j] += pr[l + j * 64];
  }
  if (WRITEH) {
    f32x4* hw = (f32x4*)(Hout + (size_t)row * DD);
    #pragma unroll
    for (int j = 0; j < 3; ++j) hw[l + j * 64] = v[j];
  }
  float s = 0.f;
  #pragma unroll
  for (int j = 0; j < 3; ++j) s += v[j][0] + v[j][1] + v[j][2] + v[j][3];
  #pragma unroll
  for (int m = 1; m < 64; m <<= 1) s += __shfl_xor(s, m, 64);
  const float mean = s * (1.f / 768.f);
  float vs = 0.f;
  #pragma unroll
  for (int j = 0; j < 3; ++j)
    #pragma unroll
    for (int e = 0; e < 4; ++e) { const float d = v[j][e] - mean; vs += d * d; }
  #pragma unroll
  for (int m = 1; m < 64; m <<= 1) vs += __shfl_xor(vs, m, 64);
  const float rstd = rsqrtf(vs * (1.f / 768.f) + eps);
  const f32x4* gp = (const f32x4*)g; const f32x4* bp = (const f32x4*)be;
  #pragma unroll
  for (int j = 0; j < 3; ++j) {
    const int c4 = l + j * 64;
    const f32x4 gg = gp[c4], bb = bp[c4];
    if (OUTBF) {
      bf16x4 o;
      #pragma unroll
      for (int e = 0; e < 4; ++e) o[e] = (__bf16)((v[j][e] - mean) * rstd * gg[e] + bb[e]);
      *(bf16x4*)(Yb + (size_t)row * DD + c4 * 4) = o;
    } else {
      f32x4 o;
      #pragma unroll
      for (int e = 0; e < 4; ++e) o[e] = (v[j][e] - mean) * rstd * gg[e] + bb[e];
      *(f32x4*)(Yf + (size_t)row * DD + c4 * 4) = o;
    }
  }
}

// ---------------------------------------------------------------------------
// im2col, vectorized: each thread owns 16 consecutive patch-cols (48 = 3x16,
// so a 16-col chunk never crosses an image-row segment): 4 x f32x4 loads +
// 2 x bf16x8 stores (was 1 scalar load + 2 B store per thread).
__global__ __launch_bounds__(256) void im2col_k(const float* __restrict__ x, __bf16* __restrict__ patches)
{
  const int idx = blockIdx.x * 256 + threadIdx.x;       // chunk id
  const int row = idx / 48, col0 = (idx % 48) * 16;
  if (row < PROWS) {
    const int b = row / 196, p = row % 196;
    const int py = p / 14, px = p % 14;
    const int r = col0 / 48, o = col0 % 48;             // offset within segment
    const float* src = x + ((size_t)(b * 224 + py * 16 + r) * 224 + px * 16) * 3 + o;
    f32x4 v[4];
    #pragma unroll
    for (int j = 0; j < 4; ++j) v[j] = *(const f32x4*)(src + j * 4);
    bf16x8 o0, o1;
    #pragma unroll
    for (int e = 0; e < 8; ++e) { o0[e] = (__bf16)v[e >> 2][e & 3]; o1[e] = (__bf16)v[2 + (e >> 2)][e & 3]; }
    *(bf16x8*)(patches + (size_t)row * 768 + col0)     = o0;
    *(bf16x8*)(patches + (size_t)row * 768 + col0 + 8) = o1;
  } else if (row < MPAD) {
    const bf16x8 z = {};
    *(bf16x8*)(patches + (size_t)row * 768 + col0)     = z;
    *(bf16x8*)(patches + (size_t)row * 768 + col0 + 8) = z;
  }
}

__global__ __launch_bounds__(256) void assemble_k(const float* __restrict__ tmp, const float* __restrict__ cls,
    const float* __restrict__ pos, float* __restrict__ h)
{
  const int idx = blockIdx.x * 256 + threadIdx.x;
  const int row = idx / 192, qc = (idx % 192) * 4;
  f32x4 v = {0.f, 0.f, 0.f, 0.f};
  if (row < MROWS) {
    const int b = row / SS, s2 = row % SS;
    if (s2 == 0) v = *(const f32x4*)(cls + qc);
    else         v = *(const f32x4*)(tmp + (size_t)(b * 196 + s2 - 1) * 768 + qc);
    const f32x4 p = *(const f32x4*)(pos + (size_t)s2 * 768 + qc);
    v += p;
  }
  *(f32x4*)(h + (size_t)row * 768 + qc) = v;
}

// ---------------------------------------------------------------------------
extern "C" void kernel_launch(void* const* d_in, const int* in_sizes, int n_in,
                              void* d_out, int out_size, void* d_ws, size_t ws_size,
                              hipStream_t stream)
{
  (void)in_sizes; (void)n_in; (void)out_size;
  const float* x    = (const float*)d_in[0];
  const float* cls  = (const float*)d_in[1];
  const float* pos  = (const float*)d_in[2];
  const float* Wp   = (const float*)d_in[3];
  const float* bp   = (const float*)d_in[4];
  const float* Wq   = (const float*)d_in[5];
  const float* bq   = (const float*)d_in[6];
  const float* Wk   = (const float*)d_in[7];
  const float* bk   = (const float*)d_in[8];
  const float* Wv   = (const float*)d_in[9];
  const float* bv   = (const float*)d_in[10];
  const float* Wo   = (const float*)d_in[11];
  const float* bo   = (const float*)d_in[12];
  const float* ln1g = (const float*)d_in[13];
  const float* ln1b = (const float*)d_in[14];
  const float* ln2g = (const float*)d_in[15];
  const float* ln2b = (const float*)d_in[16];
  const float* W1   = (const float*)d_in[17];
  const float* b1   = (const float*)d_in[18];
  const float* W2   = (const float*)d_in[19];
  const float* b2   = (const float*)d_in[20];
  const float* lnfg = (const float*)d_in[21];
  const float* lnfb = (const float*)d_in[22];

  char* ws = (char*)d_ws;
  float*  h    = (float*) (ws + 0);            // 3200x768 f32
  __bf16* y    = (__bf16*)(ws + 9830400);      // 3200x768 bf16
  __bf16* qkv  = (__bf16*)(ws + 14745600);     // 3200x2304 bf16 (v region unused)
  float*  tmp  = (float*) (ws + 14745600);     // alias: patch GEMM out
  __bf16* att  = (__bf16*)(ws + 29491200);     // 3200x768 bf16
  __bf16* mffn = (__bf16*)(ws + 34406400);     // 3200x3072 bf16
  __bf16* patches = (__bf16*)(ws + 34406400);  // alias (pre-layer only)
  __bf16* Wpb = (__bf16*)(ws + 54067200);
  __bf16* Wqb = (__bf16*)(ws + 55246848);
  __bf16* Wkb = (__bf16*)(ws + 69402624);
  __bf16* Wvb = (__bf16*)(ws + 83558400);
  __bf16* Wob = (__bf16*)(ws + 97714176);
  __bf16* W1b = (__bf16*)(ws + 111869952);
  __bf16* W2b = (__bf16*)(ws + 168493056);
  __bf16* vt  = (__bf16*)(ws + 225116160);     // 192 x 28 x 64 x 8 bf16 (5,505,024 B)
  float*  pbuf = (float*)(ws + 230621184);     // 4 x 3200x768 f32 split-K partials
  if (ws_size < 269942784) return;   // failure signature: absmax == ref absmax

  // all weight conversions in ONE dispatch, register transpose, no LDS
  w2ball_k<<<10440, 256, 0, stream>>>(Wp, Wq, Wk, Wv, Wo, W1, W2,
                                      Wpb, Wqb, Wkb, Wvb, Wob, W1b, W2b);

  im2col_k<<<MPAD * 48 / 256, 256, 0, stream>>>(x, patches);
  // patch GEMM: MODE 2 (plain store + bias, kz=0) -> no atomics, no
  // dependence on tmp being zero-initialized.
  gemm_k<64,1,2,false,false,false><<<12*32, 256, 0, stream>>>(
      patches, Wpb,Wpb,Wpb, bp,bp,bp, tmp, nullptr, nullptr, DD, DD, DD);
  assemble_k<<<MPAD * 192 / 256, 256, 0, stream>>>(tmp, cls, pos, h);

  ln_k<true><<<MROWS / 4, 256, 0, stream>>>(h, ln1g, ln1b, 1e-6f, y, nullptr);
  for (int l = 0; l < 12; ++l) {
    const size_t wDD = (size_t)l * DD * DD, wFF = (size_t)l * DD * FFD;
    // QKV (128^2 tile, 450 working blocks, K=768)
    gemm_k<128,3,0,false,true,true><<<18*32, 256, 0, stream>>>(
        y, Wqb + wDD, Wkb + wDD, Wvb + wDD,
        bq + l*DD, bk + l*DD, bv + l*DD, nullptr, qkv, vt, 3*DD, DD, DD);
    attn_k<<<dim3(4, 192), 256, 0, stream>>>(qkv, vt, att);
    // Wo: split-K x2 -> pbuf[0..1] (600 working blocks, K=384 each)
    gemm_k<64,1,2,false,false,false><<<dim3(12*32, 2), 256, 0, stream>>>(
        att, Wob + wDD, nullptr, nullptr, bo + l*DD, nullptr, nullptr,
        pbuf, nullptr, nullptr, DD, DD/2, DD);
    // h += attn_proj; y = LN2(h)
    lnsum_k<2,true,true><<<MROWS / 4, 256, 0, stream>>>(
        h, pbuf, ln2g + l*DD, ln2b + l*DD, 1e-6f, y, nullptr, h);
    // FFN1 (GELU, bf16 out)
    gemm_k<128,1,0,true,true,false><<<24*32, 256, 0, stream>>>(
        y, W1b + wFF, nullptr, nullptr, b1 + l*FFD, nullptr, nullptr,
        nullptr, mffn, nullptr, FFD, DD, DD);
    // FFN2: split-K x4 -> pbuf[0..3] (600 working blocks, K=768 each)
    gemm_k<128,1,2,false,false,false><<<dim3(6*32, 4), 256, 0, stream>>>(
        mffn, W2b + wFF, nullptr, nullptr, b2 + l*DD, nullptr, nullptr,
        pbuf, nullptr, nullptr, DD, FFD/4, FFD);
    // h += ffn; y = LN1_{l+1}(h)
    if (l < 11)
      lnsum_k<4,true,true><<<MROWS / 4, 256, 0, stream>>>(
          h, pbuf, ln1g + (l+1)*DD, ln1b + (l+1)*DD, 1e-6f, y, nullptr, h);
  }
  lnsum_k<4,false,false><<<MROWS / 4, 256, 0, stream>>>(
      h, pbuf, lnfg, lnfb, 1e-3f, nullptr, (float*)d_out, nullptr);
}

// Round 10
// 2158.614 us; speedup vs baseline: 1.1034x; 1.0340x over previous
//
#include <hip/hip_runtime.h>
#include <cstdint>
#include <cstddef>

#define DD   768
#define HHN  12
#define SS   197
#define FFD  3072
#define MROWS 3152   // B*S
#define MPAD  3200   // padded rows (25 * 128)
#define PROWS 3136   // B*196 patches
#define PSTRIDE 2457600  // 3200*768 floats: one split-K partial (padded rows)

typedef __attribute__((ext_vector_type(4))) float  f32x4;
typedef __attribute__((ext_vector_type(8))) __bf16 bf16x8;
typedef __attribute__((ext_vector_type(4))) __bf16 bf16x4;

// ---------------------------------------------------------------------------
// One 32k x 256n conversion tile: W[K][N] f32 -> Wb[k/8][n][k%8] bf16,
// pure register transpose (verified w2ball body, r7/r9). 256 threads.
__device__ __forceinline__ void conv_tile(const float* __restrict__ W,
                                          __bf16* __restrict__ Wb,
                                          int NT, int loc)
{
  const int N  = NT * 256;
  const int n0 = (loc % NT) * 256, k0 = (loc / NT) * 32;
  const int t  = threadIdx.x;
  const int kg = t >> 6;                 // 8-row group (one per wave)
  const int n  = n0 + (t & 63) * 4;      // 4 consecutive cols
  const int kb = k0 + kg * 8;
  f32x4 v[8];
  #pragma unroll
  for (int j = 0; j < 8; ++j)
    v[j] = *(const f32x4*)(W + (size_t)(kb + j) * N + n);
  __bf16* out = Wb + ((size_t)((k0 >> 3) + kg) * N + n) * 8;
  #pragma unroll
  for (int c = 0; c < 4; ++c) {
    bf16x8 o;
    #pragma unroll
    for (int j = 0; j < 8; ++j) o[j] = (__bf16)v[j][c];
    *(bf16x8*)(out + c * 8) = o;
  }
}

// ---------------------------------------------------------------------------
// Init conversion: Wp + LAYER 0's six weight matrices only (936 blocks,
// ~1/11 of the old 10440-block w2ball). The remaining layers' conversions
// ride as overlay blocks on layer-l GEMM dispatches (see gemm_k), where
// their pure-load waves overlap GEMM MFMA waves (m114 co-scheduling) —
// standalone w2ball was 135 us at 0% MFMA / 31% HBM (latency-bound).
__global__ __launch_bounds__(256) void w2binit_k(
    const float* __restrict__ Wp, const float* __restrict__ Wq, const float* __restrict__ Wk,
    const float* __restrict__ Wv, const float* __restrict__ Wo, const float* __restrict__ W1,
    const float* __restrict__ W2,
    __bf16* __restrict__ Wpb, __bf16* __restrict__ Wqb, __bf16* __restrict__ Wkb,
    __bf16* __restrict__ Wvb, __bf16* __restrict__ Wob, __bf16* __restrict__ W1b,
    __bf16* __restrict__ W2b)
{
  const int bidx = blockIdx.x;
  if      (bidx <  72) conv_tile(Wp, Wpb,  3, bidx);        // 768x768
  else if (bidx < 144) conv_tile(Wq, Wqb,  3, bidx - 72);   // layer-0 768x768
  else if (bidx < 216) conv_tile(Wk, Wkb,  3, bidx - 144);
  else if (bidx < 288) conv_tile(Wv, Wvb,  3, bidx - 216);
  else if (bidx < 360) conv_tile(Wo, Wob,  3, bidx - 288);
  else if (bidx < 648) conv_tile(W1, W1b, 12, bidx - 360);  // 768x3072
  else                 conv_tile(W2, W2b,  3, bidx - 648);  // 3072x768
}

// ---------------------------------------------------------------------------
// Pipelined bf16-MFMA GEMM (verified 128^2 structure), 2-D XCD-PATCH swizzle,
// plus CONVERSION OVERLAY: blocks with blockIdx.x >= gridDim.x - cBlocks
// (dispatched LAST -> tail-fill as GEMM blocks retire) convert next-layer
// weight tiles via conv_tile. cS*/cD* select up to 3 matrices, cPer blocks
// each. Writes (layer l+1 Wb) are disjoint from this dispatch's reads (l).
//  BN: 128 or 64. BM=128, BK=32, 4 waves, 3 LDS buffers, prefetch distance 2.
//  MODE 0: bias (+opt GELU) -> Cb bf16 / Cf f32.
//  MODE 1: legacy atomicAdd into Cf (unused).
//  MODE 2: split-K partial, plain f32 store to Cf + kz*PSTRIDE (bias kz==0).
template<int BN, int NMAT, int MODE, bool GELU_, bool STOREBF, bool VT>
__global__ __launch_bounds__(256) void gemm_k(
    const __bf16* __restrict__ A,
    const __bf16* __restrict__ Bb0, const __bf16* __restrict__ Bb1, const __bf16* __restrict__ Bb2,
    const float* __restrict__ bias0, const float* __restrict__ bias1, const float* __restrict__ bias2,
    float* __restrict__ Cf, __bf16* __restrict__ Cb, __bf16* __restrict__ vt,
    int N, int Kloc, int Kstride,
    const float* cS0, const float* cS1, const float* cS2,
    __bf16* cD0, __bf16* cD1, __bf16* cD2,
    int cNT, int cPer, int cBlocks)
{
  // ---- conversion overlay (before swizzle; conv blocks are the grid tail)
  const int gemmGrid = (int)gridDim.x - cBlocks;
  if ((int)blockIdx.x >= gemmGrid) {
    if (blockIdx.y == 0) {
      const int cl = (int)blockIdx.x - gemmGrid;
      const int mi = cl / cPer, li = cl - mi * cPer;
      conv_tile(mi == 0 ? cS0 : (mi == 1 ? cS1 : cS2),
                mi == 0 ? cD0 : (mi == 1 ? cD1 : cD2), cNT, li);
    }
    return;
  }

  // ---- 2D patch swizzle (RM=4, RN=2; requires N/BN even)
  const int xcd = blockIdx.x & 7;
  const int ib  = blockIdx.x >> 3;
  const int NT  = N / BN;
  const int pm  = xcd >> 1, pn = xcd & 1;
  const int cm  = 6 + (pm < 1 ? 1 : 0);            // 25 m-tiles: 7,6,6,6
  const int bm  = pm * 6 + (pm < 1 ? pm : 1);
  const int cn  = NT >> 1;
  if (ib >= cm * cn) return;
  const int mt  = bm + ib % cm;                    // m-fastest: B-tile reused
  const int nt  = pn * cn + ib / cm;               //   back-to-back in L2
  const int m0  = mt * 128;
  const int n0  = nt * BN;
  const int kz  = blockIdx.y;
  const size_t kOff = (size_t)kz * Kloc;

  constexpr int BUFB = (BN == 128) ? 16384 : 12288;
  __shared__ char lds[3 * BUFB];
  const int tid = threadIdx.x;

  int mat = 0, nB = n0, NBw = N;
  const __bf16* Bbp = Bb0; const float* biasp = bias0;
  if (NMAT == 3) {
    mat = n0 / DD; nB = n0 - mat * DD; NBw = DD;
    Bbp   = (mat == 0) ? Bb0   : ((mat == 1) ? Bb1   : Bb2);
    biasp = (mat == 0) ? bias0 : ((mat == 1) ? bias1 : bias2);
  }

  constexpr int NC = (BN == 128) ? 4 : 2;
  f32x4 acc[4][NC];
  const f32x4 z4 = {0.f, 0.f, 0.f, 0.f};
  #pragma unroll
  for (int i = 0; i < 4; ++i)
    #pragma unroll
    for (int j = 0; j < NC; ++j) acc[i][j] = z4;

  const int lane = tid & 63;
  const int wv = tid >> 6;
  const int wr = wv >> 1, wc = wv & 1;
  const int arow = tid & 127, akh = tid >> 7;

  const int nKB = Kloc >> 5;

  auto issue = [&](int kt, int buf) {
    const int k0 = kt << 5;
    char* Ab = lds + buf * BUFB;
    char* Bbl = Ab + 8192;
    {   // A: 2 x 16B DMA per thread
      const __bf16* ga0 = A + (size_t)(m0 + arow) * Kstride + kOff + k0 + akh * 8;
      auto g0 = (__attribute__((address_space(1))) unsigned int*)(uintptr_t)ga0;
      auto g1 = (__attribute__((address_space(1))) unsigned int*)(uintptr_t)(ga0 + 16);
      auto l0 = (__attribute__((address_space(3))) unsigned int*)(uintptr_t)(Ab + wv * 1024);
      auto l1 = (__attribute__((address_space(3))) unsigned int*)(uintptr_t)(Ab + 4096 + wv * 1024);
      __builtin_amdgcn_global_load_lds(g0, l0, 16, 0, 0);
      __builtin_amdgcn_global_load_lds(g1, l1, 16, 0, 0);
    }
    if (BN == 128) {
      #pragma unroll
      for (int r = 0; r < 2; ++r) {
        const int c = r * 256 + tid;
        const int g = c >> 7, col = c & 127;
        const __bf16* gb = Bbp + ((size_t)(((kOff + k0) >> 3) + g) * NBw + nB + col) * 8;
        auto gp = (__attribute__((address_space(1))) unsigned int*)(uintptr_t)gb;
        auto lp = (__attribute__((address_space(3))) unsigned int*)(uintptr_t)(Bbl + r * 4096 + wv * 1024);
        __builtin_amdgcn_global_load_lds(gp, lp, 16, 0, 0);
      }
    } else {
      const __bf16* gb = Bbp + ((size_t)(((kOff + k0) >> 3) + wv) * NBw + nB + lane) * 8;
      auto gp = (__attribute__((address_space(1))) unsigned int*)(uintptr_t)gb;
      auto lp = (__attribute__((address_space(3))) unsigned int*)(uintptr_t)(Bbl + wv * 1024);
      __builtin_amdgcn_global_load_lds(gp, lp, 16, 0, 0);
    }
  };

  constexpr int WAITIMM = (BN == 128) ? 0xF78 /*vmcnt(8)*/ : 0xF76 /*vmcnt(6)*/;

  issue(0, 0);
  issue(nKB > 1 ? 1 : 0, 1);

  int cb = 0, wb = 2;
  const int q = lane >> 4, r16 = lane & 15;
  for (int kb = 0; kb < nKB; ++kb) {
    __builtin_amdgcn_sched_barrier(0);
    __builtin_amdgcn_s_barrier();          // WAR: buf wb free
    const int nxt = kb + 2;
    issue(nxt < nKB ? nxt : nKB - 1, wb);  // clamped tail -> never-read buffer
    __builtin_amdgcn_s_waitcnt(WAITIMM);   // tile kb landed (this wave)
    __builtin_amdgcn_s_barrier();          // tile kb landed (all waves)
    __builtin_amdgcn_sched_barrier(0);

    const char* Ab = lds + cb * BUFB;
    const char* Bbl = Ab + 8192;
    const char* pa = Ab + q * 2048 + (wr * 64 + r16) * 16;
    const char* pb = (BN == 128) ? (Bbl + q * 2048 + (wc * 64 + r16) * 16)
                                 : (Bbl + q * 1024 + (wc * 32 + r16) * 16);
    bf16x8 af[4], bfv[NC];
    #pragma unroll
    for (int i = 0; i < 4; ++i) af[i]  = *(const bf16x8*)(pa + i * 256);
    #pragma unroll
    for (int i = 0; i < NC; ++i) bfv[i] = *(const bf16x8*)(pb + i * 256);
    #pragma unroll
    for (int ri = 0; ri < 4; ++ri)
      #pragma unroll
      for (int ci = 0; ci < NC; ++ci)
        acc[ri][ci] = __builtin_amdgcn_mfma_f32_16x16x32_bf16(af[ri], bfv[ci], acc[ri][ci], 0, 0, 0);

    cb = (cb == 2) ? 0 : cb + 1;
    wb = (wb == 2) ? 0 : wb + 1;
  }
  __builtin_amdgcn_s_waitcnt(0);   // drain tail DMAs

  // ---- epilogue: D layout col=lane&15, row=(lane>>4)*4+reg
  const int q4 = (lane >> 4) * 4, c16 = lane & 15;
  #pragma unroll
  for (int ci = 0; ci < NC; ++ci) {
    const int n = n0 + ((BN == 128) ? wc * 64 : wc * 32) + ci * 16 + c16;
    const float bsv = ((MODE == 1 || MODE == 2) && kz != 0) ? 0.f
                      : biasp[(NMAT == 3) ? (n - mat * DD) : n];
    #pragma unroll
    for (int ri = 0; ri < 4; ++ri) {
      const int mb = m0 + wr * 64 + ri * 16 + q4;
      #pragma unroll
      for (int rg = 0; rg < 4; ++rg) {
        float v = acc[ri][ci][rg] + bsv;
        const int row = mb + rg;
        if (VT && NMAT == 3 && mat == 2) {
          // scatter V into PV B-operand layout: vt[b][h][s/8][d][s%8]
          const int b = row / SS;
          if (b < 16) {
            const int s = row - b * SS;
            const int nloc = n - 2 * DD;
            const int hh = nloc >> 6, d = nloc & 63;
            vt[((size_t)(b * HHN + hh) * 28 + (s >> 3)) * 512 + d * 8 + (s & 7)] = (__bf16)v;
          }
        } else {
          const size_t off = (size_t)row * N + n;
          if (MODE == 1) {
            atomicAdd(&Cf[off], v);
          } else if (MODE == 2) {
            Cf[(size_t)kz * PSTRIDE + off] = v;   // plain partial store, no atomics
          } else {
            if (GELU_) {
              const float zz = v;
              const float a = 0.7978845608028654f * (zz + 0.044715f * zz * zz * zz);
              v = 0.5f * zz * (2.0f - 2.0f / (1.0f + __expf(2.0f * a)));
            }
            if (STOREBF) Cb[off] = (__bf16)v; else Cf[off] = v;
          }
        }
      }
    }
  }
}

// ---------------------------------------------------------------------------
// Fused MFMA attention: one block per (b, h, 64-row q-tile). grid (4, 192).
__global__ __launch_bounds__(256) void attn_k(const __bf16* __restrict__ qkv,
                                              const __bf16* __restrict__ vt,
                                              __bf16* __restrict__ att)
{
  __shared__ char als[58240];
  const int t = threadIdx.x;
  const int qt = blockIdx.x, bh = blockIdx.y;
  const int b = bh / HHN, hh = bh % HHN;
  const int r0 = qt * 64;

  bf16x8 vstage[7];
  #pragma unroll
  for (int i = 0; i < 7; ++i)
    vstage[i] = *(const bf16x8*)(vt + (size_t)bh * 14336 + (size_t)(t + i * 256) * 8);

  #pragma unroll
  for (int i = 0; i < 7; ++i) {
    const int c = t + i * 256;
    const int kh = c & 7, s = c >> 3;
    const int sg = s < SS ? s : (SS - 1);
    const bf16x8 v = *(const bf16x8*)(qkv + (size_t)(b * SS + sg) * 2304 + DD + hh * 64 + kh * 8);
    *(bf16x8*)(als + kh * 3600 + s * 16) = v;
  }
  #pragma unroll
  for (int i = 0; i < 2; ++i) {
    const int c = t + i * 256;
    const int qr = c & 63, dh8 = c >> 6;
    const int rr = r0 + qr;
    const int sg = rr < SS ? rr : (SS - 1);
    const bf16x8 v = *(const bf16x8*)(qkv + (size_t)(b * SS + sg) * 2304 + hh * 64 + dh8 * 8);
    *(bf16x8*)(als + 28800 + dh8 * 1040 + qr * 16) = v;
  }
  __syncthreads();

  const int w = t >> 6, lane = t & 63;
  const int q = lane >> 4, c16 = lane & 15;
  const f32x4 z4 = {0.f, 0.f, 0.f, 0.f};

  f32x4 acc[13];
  #pragma unroll
  for (int nt = 0; nt < 13; ++nt) acc[nt] = z4;
  #pragma unroll
  for (int kk = 0; kk < 2; ++kk) {
    const bf16x8 af = *(const bf16x8*)(als + 28800 + (kk * 4 + q) * 1040 + (w * 16 + c16) * 16);
    #pragma unroll
    for (int nt = 0; nt < 13; ++nt) {
      const bf16x8 bf_ = *(const bf16x8*)(als + (kk * 4 + q) * 3600 + (nt * 16 + c16) * 16);
      acc[nt] = __builtin_amdgcn_mfma_f32_16x16x32_bf16(af, bf_, acc[nt], 0, 0, 0);
    }
  }
  __syncthreads();   // Ks/Qs dead; LDS reused below

  float inv[4];
  #pragma unroll
  for (int rg = 0; rg < 4; ++rg) {
    float mx = -1e30f;
    #pragma unroll
    for (int nt = 0; nt < 13; ++nt) {
      const bool val = (nt < 12) || (c16 < 5);
      const float sv = acc[nt][rg] * 0.125f;
      if (val) mx = fmaxf(mx, sv);
    }
    #pragma unroll
    for (int m = 1; m < 16; m <<= 1) mx = fmaxf(mx, __shfl_xor(mx, m, 16));
    float sm = 0.f;
    #pragma unroll
    for (int nt = 0; nt < 13; ++nt) {
      const bool val = (nt < 12) || (c16 < 5);
      const float e = val ? __expf(acc[nt][rg] * 0.125f - mx) : 0.f;
      acc[nt][rg] = e; sm += e;
    }
    #pragma unroll
    for (int m = 1; m < 16; m <<= 1) sm += __shfl_xor(sm, m, 16);
    inv[rg] = 1.f / sm;
  }

  #pragma unroll
  for (int nt = 0; nt < 14; ++nt) {
    #pragma unroll
    for (int rg = 0; rg < 4; ++rg) {
      const int s = nt * 16 + c16;
      const int qr = w * 16 + q * 4 + rg;
      const float pv = (nt < 13) ? acc[nt][rg] * inv[rg] : 0.f;
      *(__bf16*)(als + (s >> 3) * 1040 + qr * 16 + (s & 7) * 2) = (__bf16)pv;
    }
  }
  #pragma unroll
  for (int i = 0; i < 7; ++i) {
    const int c = t + i * 256;
    *(bf16x8*)(als + 29120 + (c >> 6) * 1040 + (c & 63) * 16) = vstage[i];
  }
  __syncthreads();

  f32x4 o[4];
  #pragma unroll
  for (int dt = 0; dt < 4; ++dt) o[dt] = z4;
  #pragma unroll
  for (int kk = 0; kk < 7; ++kk) {
    const bf16x8 af = *(const bf16x8*)(als + (kk * 4 + q) * 1040 + (w * 16 + c16) * 16);
    #pragma unroll
    for (int dt = 0; dt < 4; ++dt) {
      const bf16x8 bf_ = *(const bf16x8*)(als + 29120 + (kk * 4 + q) * 1040 + (dt * 16 + c16) * 16);
      o[dt] = __builtin_amdgcn_mfma_f32_16x16x32_bf16(af, bf_, o[dt], 0, 0, 0);
    }
  }
  #pragma unroll
  for (int dt = 0; dt < 4; ++dt) {
    #pragma unroll
    for (int rg = 0; rg < 4; ++rg) {
      const int r = r0 + w * 16 + q * 4 + rg;
      if (r < SS)
        att[((size_t)bh * SS + r) * 64 + dt * 16 + c16] = (__bf16)o[dt][rg];
    }
  }
}

// ---------------------------------------------------------------------------
// Row LayerNorm over D=768: 256-thread blocks, 4 rows/block (wave per row).
template<bool OUTBF>
__global__ __launch_bounds__(256) void ln_k(const float* __restrict__ X,
    const float* __restrict__ g, const float* __restrict__ be, float eps,
    __bf16* __restrict__ Yb, float* __restrict__ Yf)
{
  const int row = blockIdx.x * 4 + (threadIdx.x >> 6), l = threadIdx.x & 63;
  const f32x4* xr = (const f32x4*)(X + (size_t)row * DD);
  f32x4 v[3];
  #pragma unroll
  for (int j = 0; j < 3; ++j) v[j] = xr[l + j * 64];
  float s = 0.f;
  #pragma unroll
  for (int j = 0; j < 3; ++j) s += v[j][0] + v[j][1] + v[j][2] + v[j][3];
  #pragma unroll
  for (int m = 1; m < 64; m <<= 1) s += __shfl_xor(s, m, 64);
  const float mean = s * (1.f / 768.f);
  float vs = 0.f;
  #pragma unroll
  for (int j = 0; j < 3; ++j)
    #pragma unroll
    for (int e = 0; e < 4; ++e) { const float d = v[j][e] - mean; vs += d * d; }
  #pragma unroll
  for (int m = 1; m < 64; m <<= 1) vs += __shfl_xor(vs, m, 64);
  const float rstd = rsqrtf(vs * (1.f / 768.f) + eps);
  const f32x4* gp = (const f32x4*)g; const f32x4* bp = (const f32x4*)be;
  #pragma unroll
  for (int j = 0; j < 3; ++j) {
    const int c4 = l + j * 64;
    const f32x4 gg = gp[c4], bb = bp[c4];
    if (OUTBF) {
      bf16x4 o;
      #pragma unroll
      for (int e = 0; e < 4; ++e) o[e] = (__bf16)((v[j][e] - mean) * rstd * gg[e] + bb[e]);
      *(bf16x4*)(Yb + (size_t)row * DD + c4 * 4) = o;
    } else {
      f32x4 o;
      #pragma unroll
      for (int e = 0; e < 4; ++e) o[e] = (v[j][e] - mean) * rstd * gg[e] + bb[e];
      *(f32x4*)(Yf + (size_t)row * DD + c4 * 4) = o;
    }
  }
}

// ---------------------------------------------------------------------------
// Fused split-K reduce + residual + LayerNorm: h_new = X + sum(P[0..NPART)),
// optionally write h_new back (WRITEH), then LN(h_new) -> Yb (bf16) or Yf.
template<int NPART, bool OUTBF, bool WRITEH>
__global__ __launch_bounds__(256) void lnsum_k(const float* X,
    const float* __restrict__ P, const float* __restrict__ g, const float* __restrict__ be,
    float eps, __bf16* __restrict__ Yb, float* __restrict__ Yf, float* Hout)
{
  const int row = blockIdx.x * 4 + (threadIdx.x >> 6), l = threadIdx.x & 63;
  const f32x4* xr = (const f32x4*)(X + (size_t)row * DD);
  f32x4 v[3];
  #pragma unroll
  for (int j = 0; j < 3; ++j) v[j] = xr[l + j * 64];
  #pragma unroll
  for (int p = 0; p < NPART; ++p) {
    const f32x4* pr = (const f32x4*)(P + (size_t)p * PSTRIDE + (size_t)row * DD);
    #pragma unroll
    for (int j = 0; j < 3; ++j) v[j] += pr[l + j * 64];
  }
  if (WRITEH) {
    f32x4* hw = (f32x4*)(Hout + (size_t)row * DD);
    #pragma unroll
    for (int j = 0; j < 3; ++j) hw[l + j * 64] = v[j];
  }
  float s = 0.f;
  #pragma unroll
  for (int j = 0; j < 3; ++j) s += v[j][0] + v[j][1] + v[j][2] + v[j][3];
  #pragma unroll
  for (int m = 1; m < 64; m <<= 1) s += __shfl_xor(s, m, 64);
  const float mean = s * (1.f / 768.f);
  float vs = 0.f;
  #pragma unroll
  for (int j = 0; j < 3; ++j)
    #pragma unroll
    for (int e = 0; e < 4; ++e) { const float d = v[j][e] - mean; vs += d * d; }
  #pragma unroll
  for (int m = 1; m < 64; m <<= 1) vs += __shfl_xor(vs, m, 64);
  const float rstd = rsqrtf(vs * (1.f / 768.f) + eps);
  const f32x4* gp = (const f32x4*)g; const f32x4* bp = (const f32x4*)be;
  #pragma unroll
  for (int j = 0; j < 3; ++j) {
    const int c4 = l + j * 64;
    const f32x4 gg = gp[c4], bb = bp[c4];
    if (OUTBF) {
      bf16x4 o;
      #pragma unroll
      for (int e = 0; e < 4; ++e) o[e] = (__bf16)((v[j][e] - mean) * rstd * gg[e] + bb[e]);
      *(bf16x4*)(Yb + (size_t)row * DD + c4 * 4) = o;
    } else {
      f32x4 o;
      #pragma unroll
      for (int e = 0; e < 4; ++e) o[e] = (v[j][e] - mean) * rstd * gg[e] + bb[e];
      *(f32x4*)(Yf + (size_t)row * DD + c4 * 4) = o;
    }
  }
}

// ---------------------------------------------------------------------------
// im2col, vectorized: each thread owns 16 consecutive patch-cols (48 = 3x16,
// so a 16-col chunk never crosses an image-row segment): 4 x f32x4 loads +
// 2 x bf16x8 stores.
__global__ __launch_bounds__(256) void im2col_k(const float* __restrict__ x, __bf16* __restrict__ patches)
{
  const int idx = blockIdx.x * 256 + threadIdx.x;       // chunk id
  const int row = idx / 48, col0 = (idx % 48) * 16;
  if (row < PROWS) {
    const int b = row / 196, p = row % 196;
    const int py = p / 14, px = p % 14;
    const int r = col0 / 48, o = col0 % 48;             // offset within segment
    const float* src = x + ((size_t)(b * 224 + py * 16 + r) * 224 + px * 16) * 3 + o;
    f32x4 v[4];
    #pragma unroll
    for (int j = 0; j < 4; ++j) v[j] = *(const f32x4*)(src + j * 4);
    bf16x8 o0, o1;
    #pragma unroll
    for (int e = 0; e < 8; ++e) { o0[e] = (__bf16)v[e >> 2][e & 3]; o1[e] = (__bf16)v[2 + (e >> 2)][e & 3]; }
    *(bf16x8*)(patches + (size_t)row * 768 + col0)     = o0;
    *(bf16x8*)(patches + (size_t)row * 768 + col0 + 8) = o1;
  } else if (row < MPAD) {
    const bf16x8 z = {};
    *(bf16x8*)(patches + (size_t)row * 768 + col0)     = z;
    *(bf16x8*)(patches + (size_t)row * 768 + col0 + 8) = z;
  }
}

__global__ __launch_bounds__(256) void assemble_k(const float* __restrict__ tmp, const float* __restrict__ cls,
    const float* __restrict__ pos, float* __restrict__ h)
{
  const int idx = blockIdx.x * 256 + threadIdx.x;
  const int row = idx / 192, qc = (idx % 192) * 4;
  f32x4 v = {0.f, 0.f, 0.f, 0.f};
  if (row < MROWS) {
    const int b = row / SS, s2 = row % SS;
    if (s2 == 0) v = *(const f32x4*)(cls + qc);
    else         v = *(const f32x4*)(tmp + (size_t)(b * 196 + s2 - 1) * 768 + qc);
    const f32x4 p = *(const f32x4*)(pos + (size_t)s2 * 768 + qc);
    v += p;
  }
  *(f32x4*)(h + (size_t)row * 768 + qc) = v;
}

// ---------------------------------------------------------------------------
extern "C" void kernel_launch(void* const* d_in, const int* in_sizes, int n_in,
                              void* d_out, int out_size, void* d_ws, size_t ws_size,
                              hipStream_t stream)
{
  (void)in_sizes; (void)n_in; (void)out_size;
  const float* x    = (const float*)d_in[0];
  const float* cls  = (const float*)d_in[1];
  const float* pos  = (const float*)d_in[2];
  const float* Wp   = (const float*)d_in[3];
  const float* bp   = (const float*)d_in[4];
  const float* Wq   = (const float*)d_in[5];
  const float* bq   = (const float*)d_in[6];
  const float* Wk   = (const float*)d_in[7];
  const float* bk   = (const float*)d_in[8];
  const float* Wv   = (const float*)d_in[9];
  const float* bv   = (const float*)d_in[10];
  const float* Wo   = (const float*)d_in[11];
  const float* bo   = (const float*)d_in[12];
  const float* ln1g = (const float*)d_in[13];
  const float* ln1b = (const float*)d_in[14];
  const float* ln2g = (const float*)d_in[15];
  const float* ln2b = (const float*)d_in[16];
  const float* W1   = (const float*)d_in[17];
  const float* b1   = (const float*)d_in[18];
  const float* W2   = (const float*)d_in[19];
  const float* b2   = (const float*)d_in[20];
  const float* lnfg = (const float*)d_in[21];
  const float* lnfb = (const float*)d_in[22];

  char* ws = (char*)d_ws;
  float*  h    = (float*) (ws + 0);            // 3200x768 f32
  __bf16* y    = (__bf16*)(ws + 9830400);      // 3200x768 bf16
  __bf16* qkv  = (__bf16*)(ws + 14745600);     // 3200x2304 bf16 (v region unused)
  float*  tmp  = (float*) (ws + 14745600);     // alias: patch GEMM out
  __bf16* att  = (__bf16*)(ws + 29491200);     // 3200x768 bf16
  __bf16* mffn = (__bf16*)(ws + 34406400);     // 3200x3072 bf16
  __bf16* patches = (__bf16*)(ws + 34406400);  // alias (pre-layer only)
  __bf16* Wpb = (__bf16*)(ws + 54067200);
  __bf16* Wqb = (__bf16*)(ws + 55246848);
  __bf16* Wkb = (__bf16*)(ws + 69402624);
  __bf16* Wvb = (__bf16*)(ws + 83558400);
  __bf16* Wob = (__bf16*)(ws + 97714176);
  __bf16* W1b = (__bf16*)(ws + 111869952);
  __bf16* W2b = (__bf16*)(ws + 168493056);
  __bf16* vt  = (__bf16*)(ws + 225116160);     // 192 x 28 x 64 x 8 bf16 (5,505,024 B)
  float*  pbuf = (float*)(ws + 230621184);     // 4 x 3200x768 f32 split-K partials
  if (ws_size < 269942784) return;   // failure signature: absmax == ref absmax

  // init: Wp + layer-0 weights only (936 blocks); layers 1..11 convert as
  // overlay blocks on layer 0..10 GEMM dispatches (hidden under MFMA).
  w2binit_k<<<936, 256, 0, stream>>>(Wp, Wq, Wk, Wv, Wo, W1, W2,
                                     Wpb, Wqb, Wkb, Wvb, Wob, W1b, W2b);

  im2col_k<<<MPAD * 48 / 256, 256, 0, stream>>>(x, patches);
  gemm_k<64,1,2,false,false,false><<<12*32, 256, 0, stream>>>(
      patches, Wpb,Wpb,Wpb, bp,bp,bp, tmp, nullptr, nullptr, DD, DD, DD,
      nullptr,nullptr,nullptr, nullptr,nullptr,nullptr, 1, 1, 0);
  assemble_k<<<MPAD * 192 / 256, 256, 0, stream>>>(tmp, cls, pos, h);

  ln_k<true><<<MROWS / 4, 256, 0, stream>>>(h, ln1g, ln1b, 1e-6f, y, nullptr);
  for (int l = 0; l < 12; ++l) {
    const size_t wDD = (size_t)l * DD * DD, wFF = (size_t)l * DD * FFD;
    const bool cv = (l < 11);
    const size_t nDD = (size_t)(l + 1) * DD * DD, nFF = (size_t)(l + 1) * DD * FFD;

    // QKV (450 working blocks, K=768) + overlay: convert Wq/Wk/Wv of l+1
    gemm_k<128,3,0,false,true,true><<<dim3(18*32 + (cv ? 216 : 0)), 256, 0, stream>>>(
        y, Wqb + wDD, Wkb + wDD, Wvb + wDD,
        bq + l*DD, bk + l*DD, bv + l*DD, nullptr, qkv, vt, 3*DD, DD, DD,
        cv ? Wq + nDD : nullptr, cv ? Wk + nDD : nullptr, cv ? Wv + nDD : nullptr,
        cv ? Wqb + nDD : nullptr, cv ? Wkb + nDD : nullptr, cv ? Wvb + nDD : nullptr,
        3, 72, cv ? 216 : 0);
    attn_k<<<dim3(4, 192), 256, 0, stream>>>(qkv, vt, att);
    // Wo: split-K x2 -> pbuf[0..1] + overlay: convert Wo of l+1
    gemm_k<64,1,2,false,false,false><<<dim3(12*32 + (cv ? 72 : 0), 2), 256, 0, stream>>>(
        att, Wob + wDD, nullptr, nullptr, bo + l*DD, nullptr, nullptr,
        pbuf, nullptr, nullptr, DD, DD/2, DD,
        cv ? Wo + nDD : nullptr, nullptr, nullptr,
        cv ? Wob + nDD : nullptr, nullptr, nullptr,
        3, 72, cv ? 72 : 0);
    // h += attn_proj; y = LN2(h)
    lnsum_k<2,true,true><<<MROWS / 4, 256, 0, stream>>>(
        h, pbuf, ln2g + l*DD, ln2b + l*DD, 1e-6f, y, nullptr, h);
    // FFN1 (GELU, bf16 out) + overlay: convert W1 of l+1
    gemm_k<128,1,0,true,true,false><<<dim3(24*32 + (cv ? 288 : 0)), 256, 0, stream>>>(
        y, W1b + wFF, nullptr, nullptr, b1 + l*FFD, nullptr, nullptr,
        nullptr, mffn, nullptr, FFD, DD, DD,
        cv ? W1 + nFF : nullptr, nullptr, nullptr,
        cv ? W1b + nFF : nullptr, nullptr, nullptr,
        12, 288, cv ? 288 : 0);
    // FFN2: split-K x4 -> pbuf[0..3] + overlay: convert W2 of l+1
    gemm_k<128,1,2,false,false,false><<<dim3(6*32 + (cv ? 288 : 0), 4), 256, 0, stream>>>(
        mffn, W2b + wFF, nullptr, nullptr, b2 + l*DD, nullptr, nullptr,
        pbuf, nullptr, nullptr, DD, FFD/4, FFD,
        cv ? W2 + nFF : nullptr, nullptr, nullptr,
        cv ? W2b + nFF : nullptr, nullptr, nullptr,
        3, 288, cv ? 288 : 0);
    // h += ffn; y = LN1_{l+1}(h)
    if (l < 11)
      lnsum_k<4,true,true><<<MROWS / 4, 256, 0, stream>>>(
          h, pbuf, ln1g + (l+1)*DD, ln1b + (l+1)*DD, 1e-6f, y, nullptr, h);
  }
  lnsum_k<4,false,false><<<MROWS / 4, 256, 0, stream>>>(
      h, pbuf, lnfg, lnfb, 1e-3f, nullptr, (float*)d_out, nullptr);
}